// Round 9
// baseline (99.958 us; speedup 1.0000x reference)
//
#include <hip/hip_runtime.h>
#include <math.h>

// AR-GAS Student-t filter, K = 4194304 sequential steps.
// Chunked scan with burn-in (contractive map). R9: latency model finally
// fits — per-step chain ~106 cy (v_rcp_f32 dominated); per-SIMD time =
// max(steps*106 per wave, 2cy*instr issue). Streams/SIMD = 64/CHUNK, so
// CHUNK 32->16 (4 waves/SIMD) balances latency (112*106=11.9k cy) against
// the issue floor (4*112*26=11.6k cy): step-term 5.65 -> ~4.9 us. BURN 96
// (empirically absmax = 1 bf16 ULP since R1). 1024 blocks x 256 thr,
// 38.5 KB LDS -> 4 blocks/CU. Swizzle +4-per-16 (b128-capable), ping-pong
// run prefetch, in-place mu writeback, separate sigma LDS region.

#define CHUNK  16
#define BURN   96
#define NRUN   (BURN / CHUNK)            // 6 burn runs
#define BLOCK  256
#define OUTW   (BLOCK * CHUNK)           // 4096 outputs per block
#define REGION (OUTW + BURN)             // 4192 staged y elements
#define SWZ(e)  ((e) + 4 * ((e) >> 4))   // +4 floats per 16; keeps 16B align
#define SWZ32(e) ((e) + 4 * ((e) >> 5))  // sigma region: +4 per 32
#define SY_PAD 5240                      // > SWZ(REGION-1) = 5235
#define SZ_PAD 4608                      // > SWZ32(OUTW-1) = 4603

__global__ __launch_bounds__(BLOCK, 4)
void ar_gas_kernel(const float* __restrict__ y,
                   const float* __restrict__ p_last_mu,
                   const float* __restrict__ p_last_s2,
                   const float* __restrict__ p_amu,
                   const float* __restrict__ p_as,
                   const float* __restrict__ p_bmu,
                   const float* __restrict__ p_bs,
                   const float* __restrict__ p_wmu,
                   const float* __restrict__ p_ws,
                   const float* __restrict__ p_nu,
                   const float* __restrict__ p_str,
                   float* __restrict__ out,
                   int n)
{
    __shared__ __align__(16) float sy[SY_PAD];   // staged y; mu in-place
    __shared__ __align__(16) float sz[SZ_PAD];   // sigma staging
    const int t     = threadIdx.x;
    const int blk   = blockIdx.x;
    const int gbase = blk * OUTW - BURN;         // global index of LDS elem 0

    const float nu       = *p_nu;
    const float strength = *p_str;
    const float a_mu = (*p_amu) * strength;
    const float a_s  = (*p_as)  * strength;
    const float b_mu = *p_bmu;
    const float b_s  = *p_bs;
    const float w_mu = *p_wmu;
    const float w_s  = *p_ws;

    // u = nu*s2 transform (algebraically == reference):
    //   r=y-mu; den=u+r^2; t2=u*r/den
    //   mu' = w_mu + b_mu*mu + (b_mu*a_mu*k1)*t2,   k1=(nu+1)/nu
    //   u'  = nu*w_s + b_s*(1-a_s)*u + (nu*b_s*a_s*k1)*(t2*r); sigma=sqrt(u/nu)
    const float inv_nu = __builtin_amdgcn_rcpf(nu);
    const float k1   = (nu + 1.0f) * inv_nu;
    const float bamk = b_mu * a_mu * k1;
    const float bask = nu * b_s * a_s * k1;
    const float c3   = b_s * (1.0f - a_s);
    const float wsn  = nu * w_s;

    // ---- stage y region: coalesced float4 global loads -> swizzled LDS ----
    #pragma unroll
    for (int it = 0; it < 5; ++it) {
        int idx = (t + BLOCK * it) * 4;          // idx%16 in {0,4,8,12}
        if (idx < REGION) {
            int g = gbase + idx;
            float4 v = make_float4(0.f, 0.f, 0.f, 0.f);
            if (g >= 0) v = *(const float4*)(y + g);   // block-0 pre-pad = 0
            *(float4*)(sy + SWZ(idx)) = v;
        }
    }
    __syncthreads();

    // ---- initial state ----
    // thread t: burn elems [16t, 16t+96), emit elems [16t+96, 16t+112).
    // block 0: burn-start global = 16t-96 <= 0 for t<=6 -> exact seed; the
    // first (6-t) runs step over zero-pad and are undone by predicated hold.
    int skipR = 0;
    float mu, u;
    if (blk == 0 && t <= NRUN) {
        mu    = *p_last_mu;
        u     = nu * (*p_last_s2);   // "last_sigma" is the variance
        skipR = NRUN - t;
    } else {                         // stationary guess; 96-step burn erases it
        mu = w_mu * __builtin_amdgcn_rcpf(fmaxf(1.0f - b_mu, 1e-12f));
        u  = wsn  * __builtin_amdgcn_rcpf(fmaxf(1.0f - b_s,  1e-12f));
    }
    const float muS = mu, uS = u;    // seed copy for predicated hold

#define STEP(yv) do {                                   \
        float r   = (yv) - mu;                          \
        float den = fmaf(r, r, u);                      \
        float inv = __builtin_amdgcn_rcpf(den);         \
        float t2  = (u * r) * inv;                      \
        mu = fmaf(bamk, t2, fmaf(b_mu, mu, w_mu));      \
        u  = fmaf(bask, t2 * r, fmaf(c3, u, wsn));      \
    } while (0)
#define LDRUN(B, off) do { _Pragma("unroll")                         \
        for (int k = 0; k < 4; ++k)                                  \
            B[k] = *(const float4*)(sy + (off) + 4 * k); } while (0)
#define RUN16(B) do { _Pragma("unroll")                              \
        for (int k = 0; k < 4; ++k) {                                \
            STEP(B[k].x); STEP(B[k].y); STEP(B[k].z); STEP(B[k].w);  \
        } } while (0)

    // ---- burn-in: 6 runs of 16 steps, ping-pong run-level prefetch ----
    const int q0 = 20 * t;           // padded base: SWZ(16t); run r at q0+20r
    float4 P[4], Q[4];
    LDRUN(P, q0);
    LDRUN(Q, q0 + 20);
    RUN16(P);  if (0 < skipR) { mu = muS; u = uS; }
    LDRUN(P, q0 + 40);
    RUN16(Q);  if (1 < skipR) { mu = muS; u = uS; }
    LDRUN(Q, q0 + 60);
    RUN16(P);  if (2 < skipR) { mu = muS; u = uS; }
    LDRUN(P, q0 + 80);
    RUN16(Q);  if (3 < skipR) { mu = muS; u = uS; }
    LDRUN(Q, q0 + 100);
    RUN16(P);  if (4 < skipR) { mu = muS; u = uS; }
    LDRUN(P, q0 + 120);              // emit-run data: own slots, safe pre-barrier
    RUN16(Q);  if (5 < skipR) { mu = muS; u = uS; }

    // all cross-thread burn reads must complete before in-place mu writes:
    __syncthreads();

    // ---- emit: 16 steps; mu in-place over consumed y; sigma -> sz ----
    {
        const int pe = q0 + 120;             // SWZ(16t + 96)
        const int ze = 16 * t + 4 * (t >> 1); // SWZ32(16t); run stays contiguous
        float4 m, s;
        #pragma unroll
        for (int g = 0; g < 4; ++g) {
            STEP(P[g].x); m.x = mu; s.x = __builtin_amdgcn_sqrtf(u * inv_nu);
            STEP(P[g].y); m.y = mu; s.y = __builtin_amdgcn_sqrtf(u * inv_nu);
            STEP(P[g].z); m.z = mu; s.z = __builtin_amdgcn_sqrtf(u * inv_nu);
            STEP(P[g].w); m.w = mu; s.w = __builtin_amdgcn_sqrtf(u * inv_nu);
            *(float4*)(sy + pe + 4 * g) = m;
            *(float4*)(sz + ze + 4 * g) = s;
        }
    }
#undef RUN16
#undef LDRUN
#undef STEP
    __syncthreads();

    // ---- coalesced float4 copy-out of both outputs ----
    const int obase = blk * OUTW;
    #pragma unroll
    for (int it = 0; it < 4; ++it) {
        int o  = (t + BLOCK * it) * 4;
        int f  = SWZ(o) + 120;               // SWZ(o + 96), 4 contiguous
        int fz = SWZ32(o);
        *(float4*)(out + obase + o) =
            make_float4(sy[f], sy[f + 1], sy[f + 2], sy[f + 3]);
        *(float4*)(out + n + obase + o) =
            make_float4(sz[fz], sz[fz + 1], sz[fz + 2], sz[fz + 3]);
    }
}

extern "C" void kernel_launch(void* const* d_in, const int* in_sizes, int n_in,
                              void* d_out, int out_size, void* d_ws, size_t ws_size,
                              hipStream_t stream) {
    const float* y = (const float*)d_in[0];
    const int n    = in_sizes[0];              // 4194304 = 1024 * 4096
    const int grid = n / OUTW;                 // 1024 blocks

    ar_gas_kernel<<<grid, BLOCK, 0, stream>>>(
        y,
        (const float*)d_in[1],  // last_mu
        (const float*)d_in[2],  // last_sigma (variance)
        (const float*)d_in[3],  // alpha_mu
        (const float*)d_in[4],  // alpha_sigma
        (const float*)d_in[5],  // beta_mu
        (const float*)d_in[6],  // beta_sigma
        (const float*)d_in[7],  // omega_mu
        (const float*)d_in[8],  // omega_sigma
        (const float*)d_in[9],  // nu
        (const float*)d_in[10], // norm_strength
        (float*)d_out, n);
}